// Round 1
// baseline (1927.041 us; speedup 1.0000x reference)
//
#include <hip/hip_runtime.h>

#define NN 50000
#define NE 800000
#define CC 16
#define FEAT 8
#define NG 64
#define ZCOLS 144   // 8 edge-feature blocks of 16 + 1 bias block of 16

// ---------------------------------------------------------------------------
// Z kernel: Z[v, f*16+o] = sum_i x[v,i] * we[f, i*16+o]   (f<8)
//           Z[v, 128+o]  = sum_i x[v,i] * be[i*16+o]
// One thread per (v, group-of-4 cols). Weights staged in LDS (broadcast reads).
// ---------------------------------------------------------------------------
__global__ __launch_bounds__(256) void zk(const float* __restrict__ x,
                                          const float* __restrict__ we,
                                          const float* __restrict__ be,
                                          float* __restrict__ Z) {
    __shared__ float w[16 * ZCOLS];  // w[i*144 + f*16 + o]
    for (int t = threadIdx.x; t < 16 * ZCOLS; t += blockDim.x) {
        int i = t / ZCOLS, c = t % ZCOLS;
        int f = c >> 4, o = c & 15;
        w[t] = (f < FEAT) ? we[f * 256 + i * 16 + o] : be[i * 16 + o];
    }
    __syncthreads();
    int idx = blockIdx.x * blockDim.x + threadIdx.x;   // (v, c4)
    if (idx >= NN * 36) return;
    int v = idx / 36, c4 = idx % 36;
    const float* xv = x + (size_t)v * 16;
    float4 acc = {0.f, 0.f, 0.f, 0.f};
#pragma unroll
    for (int i = 0; i < 16; i++) {
        float xi = xv[i];
        float4 wv = *(const float4*)&w[i * ZCOLS + c4 * 4];
        acc.x += xi * wv.x; acc.y += xi * wv.y;
        acc.z += xi * wv.z; acc.w += xi * wv.w;
    }
    *(float4*)&Z[(size_t)v * ZCOLS + c4 * 4] = acc;
}

// ---------------------------------------------------------------------------
// Degree histogram: deg[dst[e]] += 1
// ---------------------------------------------------------------------------
__global__ __launch_bounds__(256) void degk(const int* __restrict__ dst,
                                            float* __restrict__ deg) {
    int e = blockIdx.x * blockDim.x + threadIdx.x;
    if (e < NE) atomicAdd(&deg[dst[e]], 1.0f);
}

// ---------------------------------------------------------------------------
// Edge kernel: msg[e,o] = sum_{f<8} ea[e,f]*Z[src,f*16+o] + Z[src,128+o]
//              agg[dst,o] += msg[e,o]
// ---------------------------------------------------------------------------
__global__ __launch_bounds__(256) void ek(const float* __restrict__ Z,
                                          const float* __restrict__ ea,
                                          const int* __restrict__ src,
                                          const int* __restrict__ dst,
                                          float* __restrict__ agg) {
    int e = blockIdx.x * blockDim.x + threadIdx.x;
    if (e >= NE) return;
    int s = src[e], d = dst[e];
    const float4* zr = (const float4*)(Z + (size_t)s * ZCOLS);
    float4 e0 = *(const float4*)(ea + (size_t)e * 8);
    float4 e1 = *(const float4*)(ea + (size_t)e * 8 + 4);
    float cf[8] = {e0.x, e0.y, e0.z, e0.w, e1.x, e1.y, e1.z, e1.w};
    // init with the bias block (cols 128..143)
    float4 a0 = zr[32], a1 = zr[33], a2 = zr[34], a3 = zr[35];
    float acc[16] = {a0.x, a0.y, a0.z, a0.w, a1.x, a1.y, a1.z, a1.w,
                     a2.x, a2.y, a2.z, a2.w, a3.x, a3.y, a3.z, a3.w};
#pragma unroll
    for (int f = 0; f < 8; f++) {
        float c = cf[f];
#pragma unroll
        for (int q = 0; q < 4; q++) {
            float4 z = zr[f * 4 + q];
            acc[q * 4 + 0] += c * z.x;
            acc[q * 4 + 1] += c * z.y;
            acc[q * 4 + 2] += c * z.z;
            acc[q * 4 + 3] += c * z.w;
        }
    }
    float* ag = agg + (size_t)d * 16;
#pragma unroll
    for (int o = 0; o < 16; o++) atomicAdd(&ag[o], acc[o]);
}

// ---------------------------------------------------------------------------
// Node kernel: h[v,o] = sum_i xin[v,i]*root[i,o] + agg[v,o]/max(deg,1) + bias[o]
// POOL=false: write h1, and (o==0) count nodes per graph.
// POOL=true : atomicAdd h into gsum[batch[v]*16+o].
// ---------------------------------------------------------------------------
template <bool POOL>
__global__ __launch_bounds__(256) void nk(const float* __restrict__ xin,
                                          const float* __restrict__ root,
                                          const float* __restrict__ bias,
                                          const float* __restrict__ agg,
                                          const float* __restrict__ deg,
                                          const int* __restrict__ batch,
                                          float* __restrict__ outp,
                                          float* __restrict__ gcnt) {
    __shared__ float r[256];
    __shared__ float b[16];
    if (threadIdx.x < 256) r[threadIdx.x] = root[threadIdx.x];
    if (threadIdx.x < 16) b[threadIdx.x] = bias[threadIdx.x];
    __syncthreads();
    int idx = blockIdx.x * blockDim.x + threadIdx.x;
    if (idx >= NN * 16) return;
    int v = idx >> 4, o = idx & 15;
    const float* xv = xin + (size_t)v * 16;
    float acc = b[o] + agg[idx] / fmaxf(deg[v], 1.0f);
#pragma unroll
    for (int i = 0; i < 16; i++) acc += xv[i] * r[i * 16 + o];
    if (POOL) {
        int g = batch[v];
        atomicAdd(&outp[g * 16 + o], acc);
    } else {
        outp[idx] = acc;
        if (o == 0) atomicAdd(&gcnt[batch[v]], 1.0f);
    }
}

// ---------------------------------------------------------------------------
// Final: out[g*16+o] = gsum[g*16+o] / max(gcnt[g], 1)
// ---------------------------------------------------------------------------
__global__ void fink(const float* __restrict__ gsum,
                     const float* __restrict__ gcnt,
                     float* __restrict__ out) {
    int i = blockIdx.x * blockDim.x + threadIdx.x;
    if (i < NG * 16) out[i] = gsum[i] / fmaxf(gcnt[i >> 4], 1.0f);
}

extern "C" void kernel_launch(void* const* d_in, const int* in_sizes, int n_in,
                              void* d_out, int out_size, void* d_ws, size_t ws_size,
                              hipStream_t stream) {
    const float* x     = (const float*)d_in[0];
    const int*   ei    = (const int*)d_in[1];
    const float* ea    = (const float*)d_in[2];
    const int*   batch = (const int*)d_in[3];
    const float* we1   = (const float*)d_in[4];
    const float* be1   = (const float*)d_in[5];
    const float* root1 = (const float*)d_in[6];
    const float* bias1 = (const float*)d_in[7];
    const float* we2   = (const float*)d_in[8];
    const float* be2   = (const float*)d_in[9];
    const float* root2 = (const float*)d_in[10];
    const float* bias2 = (const float*)d_in[11];

    float* ws   = (float*)d_ws;
    float* Z    = ws;                                  // NN*144
    float* h1   = Z + (size_t)NN * ZCOLS;              // NN*16
    float* agg1 = h1 + (size_t)NN * 16;                // NN*16
    float* agg2 = agg1 + (size_t)NN * 16;              // NN*16
    float* deg  = agg2 + (size_t)NN * 16;              // NN
    float* gsum = deg + NN;                            // NG*16
    float* gcnt = gsum + NG * 16;                      // NG

    // zero the accumulators (agg1, agg2, deg, gsum, gcnt are contiguous)
    size_t zbytes = ((size_t)NN * 16 * 2 + NN + NG * 16 + NG) * sizeof(float);
    hipMemsetAsync(agg1, 0, zbytes, stream);

    const int* src = ei;
    const int* dst = ei + NE;

    dim3 blk(256);
    int gE = (NE + 255) / 256;
    int gZ = (NN * 36 + 255) / 256;
    int gV = (NN * 16 + 255) / 256;

    degk<<<gE, blk, 0, stream>>>(dst, deg);

    // ---- layer 1 ----
    zk<<<gZ, blk, 0, stream>>>(x, we1, be1, Z);
    ek<<<gE, blk, 0, stream>>>(Z, ea, src, dst, agg1);
    nk<false><<<gV, blk, 0, stream>>>(x, root1, bias1, agg1, deg, batch, h1, gcnt);

    // ---- layer 2 ----
    zk<<<gZ, blk, 0, stream>>>(h1, we2, be2, Z);
    ek<<<gE, blk, 0, stream>>>(Z, ea, src, dst, agg2);
    nk<true><<<gV, blk, 0, stream>>>(h1, root2, bias2, agg2, deg, batch, gsum, gcnt);

    fink<<<4, blk, 0, stream>>>(gsum, gcnt, (float*)d_out);
}

// Round 3
// 241.297 us; speedup vs baseline: 7.9862x; 7.9862x over previous
//
#include <hip/hip_runtime.h>

#define NN 50000
#define NE 800000
#define NG 64

// ---------------------------------------------------------------------------
// deg histogram (int)
// ---------------------------------------------------------------------------
__global__ __launch_bounds__(256) void histk(const int* __restrict__ dst,
                                             int* __restrict__ deg) {
    int e = blockIdx.x * 256 + threadIdx.x;
    if (e < NE) atomicAdd(&deg[dst[e]], 1);
}

// ---------------------------------------------------------------------------
// single-block exclusive scan of deg[NN] -> row[NN+1], cur[NN]=row[NN]
// ---------------------------------------------------------------------------
__global__ __launch_bounds__(1024) void scank(const int* __restrict__ deg,
                                              int* __restrict__ row,
                                              int* __restrict__ cur) {
    __shared__ int buf[1024];
    int tid = threadIdx.x;
    int carry = 0;
    for (int base = 0; base < NN; base += 8192) {
        int x[8];
        int s = 0;
#pragma unroll
        for (int k = 0; k < 8; k++) {
            int idx = base + tid * 8 + k;
            x[k] = (idx < NN) ? deg[idx] : 0;
            s += x[k];
        }
        buf[tid] = s;
        __syncthreads();
        for (int off = 1; off < 1024; off <<= 1) {
            int t = buf[tid];
            if (tid >= off) t += buf[tid - off];
            __syncthreads();
            buf[tid] = t;
            __syncthreads();
        }
        int incl = buf[tid];
        int tot = buf[1023];
        int run = carry + incl - s;
#pragma unroll
        for (int k = 0; k < 8; k++) {
            int idx = base + tid * 8 + k;
            if (idx < NN) { row[idx] = run; cur[idx] = run; run += x[k]; }
        }
        carry += tot;
        __syncthreads();
    }
    if (tid == 0) row[NN] = NE;
}

// ---------------------------------------------------------------------------
// scatter edges into CSR order: src_s[pos], ea_s[pos*8..]
// ---------------------------------------------------------------------------
__global__ __launch_bounds__(256) void scatk(const int* __restrict__ src,
                                             const int* __restrict__ dst,
                                             const float* __restrict__ ea,
                                             int* __restrict__ cur,
                                             int* __restrict__ src_s,
                                             float* __restrict__ ea_s) {
    int e = blockIdx.x * 256 + threadIdx.x;
    if (e >= NE) return;
    int d = dst[e];
    int pos = atomicAdd(&cur[d], 1);
    src_s[pos] = src[e];
    float4 a = *(const float4*)(ea + (size_t)e * 8);
    float4 b = *(const float4*)(ea + (size_t)e * 8 + 4);
    *(float4*)(ea_s + (size_t)pos * 8) = a;
    *(float4*)(ea_s + (size_t)pos * 8 + 4) = b;
}

// ---------------------------------------------------------------------------
// edge phase: P[v,f,i] = sum_{e->v} ea[e,f]*x[src_e,i];  S[v,i] = sum x[src_e,i]
// 16 threads per node (thread t owns i=t), no atomics (CSR).
// ---------------------------------------------------------------------------
__global__ __launch_bounds__(256) void edgek(const float* __restrict__ xin,
                                             const int* __restrict__ row,
                                             const int* __restrict__ srcs,
                                             const float* __restrict__ eas,
                                             float* __restrict__ P,
                                             float* __restrict__ S) {
    int g = threadIdx.x >> 4, t = threadIdx.x & 15;
    int v = blockIdx.x * 16 + g;
    int r0 = row[v], r1 = row[v + 1];
    float p0 = 0.f, p1 = 0.f, p2 = 0.f, p3 = 0.f;
    float p4 = 0.f, p5 = 0.f, p6 = 0.f, p7 = 0.f, s = 0.f;
    for (int pos = r0; pos < r1; ++pos) {
        int sn = srcs[pos];
        float xv = xin[(size_t)sn * 16 + t];
        float4 a = *(const float4*)(eas + (size_t)pos * 8);
        float4 b = *(const float4*)(eas + (size_t)pos * 8 + 4);
        p0 += a.x * xv; p1 += a.y * xv; p2 += a.z * xv; p3 += a.w * xv;
        p4 += b.x * xv; p5 += b.y * xv; p6 += b.z * xv; p7 += b.w * xv;
        s += xv;
    }
    float* pv = P + (size_t)v * 128;
    pv[0 * 16 + t] = p0; pv[1 * 16 + t] = p1; pv[2 * 16 + t] = p2; pv[3 * 16 + t] = p3;
    pv[4 * 16 + t] = p4; pv[5 * 16 + t] = p5; pv[6 * 16 + t] = p6; pv[7 * 16 + t] = p7;
    S[(size_t)v * 16 + t] = s;
}

// ---------------------------------------------------------------------------
// node phase: h[v,o] = x[v]@root + (P[v]@we + S[v]@be)/max(deg,1) + bias
// POOL=false -> write h; POOL=true -> block-LDS pool into gsum/gcnt.
// LDS weight matrix stored per-o column, stride 164 (kills 16-way conflicts).
// ---------------------------------------------------------------------------
#define WSTR 164
template <bool POOL>
__global__ __launch_bounds__(256) void nodek(const float* __restrict__ xin,
                                             const float* __restrict__ P,
                                             const float* __restrict__ S,
                                             const float* __restrict__ we,
                                             const float* __restrict__ be,
                                             const float* __restrict__ root,
                                             const float* __restrict__ bias,
                                             const int* __restrict__ deg,
                                             const int* __restrict__ batch,
                                             float* __restrict__ out,
                                             float* __restrict__ gsum,
                                             float* __restrict__ gcnt) {
    __shared__ float wt[16 * WSTR];
    __shared__ float bs[16];
    __shared__ float gacc[16][16];
    __shared__ int gcnta[16];
    int tid = threadIdx.x;
    for (int idx = tid; idx < 2048; idx += 256) {
        int f = idx >> 8, i = (idx >> 4) & 15, o = idx & 15;
        wt[o * WSTR + f * 16 + i] = we[idx];
    }
    {
        int i = tid >> 4, o = tid & 15;
        wt[o * WSTR + 128 + i] = be[tid];
        wt[o * WSTR + 144 + i] = root[tid];
    }
    if (tid < 16) bs[tid] = bias[tid];
    if (POOL) {
        gacc[tid >> 4][tid & 15] = 0.f;
        if (tid < 16) gcnta[tid] = 0;
    }
    __syncthreads();
    int g = tid >> 4, o = tid & 15;
    int v = blockIdx.x * 16 + g;

    const float4* pv = (const float4*)(P + (size_t)v * 128);
    const float4* wc = (const float4*)(wt + o * WSTR);
    float acc = 0.f;
#pragma unroll
    for (int k = 0; k < 32; k++) {
        float4 a = pv[k]; float4 w = wc[k];
        acc += a.x * w.x + a.y * w.y + a.z * w.z + a.w * w.w;
    }
    const float4* sv = (const float4*)(S + (size_t)v * 16);
#pragma unroll
    for (int k = 0; k < 4; k++) {
        float4 a = sv[k]; float4 w = wc[32 + k];
        acc += a.x * w.x + a.y * w.y + a.z * w.z + a.w * w.w;
    }
    float r = 0.f;
    const float4* xv = (const float4*)(xin + (size_t)v * 16);
#pragma unroll
    for (int k = 0; k < 4; k++) {
        float4 a = xv[k]; float4 w = wc[36 + k];
        r += a.x * w.x + a.y * w.y + a.z * w.z + a.w * w.w;
    }
    int dg = deg[v];
    float h = r + acc / (float)(dg > 1 ? dg : 1) + bs[o];

    if (!POOL) {
        out[(size_t)v * 16 + o] = h;
    } else {
        int bmin = batch[blockIdx.x * 16];
        int b = batch[v];
        int slot = b - bmin;
        if (slot < 16) {
            atomicAdd(&gacc[slot][o], h);
            if (o == 0) atomicAdd(&gcnta[slot], 1);
        } else {
            atomicAdd(&gsum[(size_t)b * 16 + o], h);
            if (o == 0) atomicAdd(&gcnt[b], 1.0f);
        }
        __syncthreads();
        if (gcnta[g] > 0) {
            atomicAdd(&gsum[(size_t)(bmin + g) * 16 + o], gacc[g][o]);
            if (o == 0) atomicAdd(&gcnt[bmin + g], (float)gcnta[g]);
        }
    }
}

// ---------------------------------------------------------------------------
// final divide over all NG*16 = 1024 outputs (4 blocks x 256 — Round-2 bug
// was launching only 1 block here, leaving graphs 16..63 zeroed)
// ---------------------------------------------------------------------------
__global__ void fink(const float* __restrict__ gsum,
                     const float* __restrict__ gcnt,
                     float* __restrict__ out) {
    int i = blockIdx.x * 256 + threadIdx.x;
    if (i < NG * 16) out[i] = gsum[i] / fmaxf(gcnt[i >> 4], 1.0f);
}

extern "C" void kernel_launch(void* const* d_in, const int* in_sizes, int n_in,
                              void* d_out, int out_size, void* d_ws, size_t ws_size,
                              hipStream_t stream) {
    const float* x     = (const float*)d_in[0];
    const int*   ei    = (const int*)d_in[1];
    const float* ea    = (const float*)d_in[2];
    const int*   batch = (const int*)d_in[3];
    const float* we1   = (const float*)d_in[4];
    const float* be1   = (const float*)d_in[5];
    const float* root1 = (const float*)d_in[6];
    const float* bias1 = (const float*)d_in[7];
    const float* we2   = (const float*)d_in[8];
    const float* be2   = (const float*)d_in[9];
    const float* root2 = (const float*)d_in[10];
    const float* bias2 = (const float*)d_in[11];

    float* ws = (float*)d_ws;
    float* P    = ws;                                   // NN*128
    float* ea_s = P + (size_t)NN * 128;                 // NE*8
    float* h1   = ea_s + (size_t)NE * 8;                // NN*16
    float* S    = h1 + (size_t)NN * 16;                 // NN*16
    int*   src_s = (int*)(S + (size_t)NN * 16);         // NE
    int*   row   = src_s + NE;                          // NN+1
    int*   cur   = row + NN + 1;                        // NN
    int*   deg   = cur + NN;                            // NN
    float* gsum  = (float*)(deg + NN);                  // NG*16
    float* gcnt  = gsum + NG * 16;                      // NG

    // zero deg + gsum + gcnt (contiguous)
    hipMemsetAsync(deg, 0, (size_t)(NN + NG * 16 + NG) * 4, stream);

    const int* src = ei;
    const int* dst = ei + NE;

    int gE = (NE + 255) / 256;   // 3125
    int gV = NN / 16;            // 3125 (exact: 50000/16)

    histk<<<gE, 256, 0, stream>>>(dst, deg);
    scank<<<1, 1024, 0, stream>>>(deg, row, cur);
    scatk<<<gE, 256, 0, stream>>>(src, dst, ea, cur, src_s, ea_s);

    // layer 1
    edgek<<<gV, 256, 0, stream>>>(x, row, src_s, ea_s, P, S);
    nodek<false><<<gV, 256, 0, stream>>>(x, P, S, we1, be1, root1, bias1,
                                         deg, batch, h1, gsum, gcnt);
    // layer 2
    edgek<<<gV, 256, 0, stream>>>(h1, row, src_s, ea_s, P, S);
    nodek<true><<<gV, 256, 0, stream>>>(h1, P, S, we2, be2, root2, bias2,
                                        deg, batch, h1 /*unused*/, gsum, gcnt);

    fink<<<4, 256, 0, stream>>>(gsum, gcnt, (float*)d_out);
}